// Round 8
// baseline (220.883 us; speedup 1.0000x reference)
//
#include <hip/hip_runtime.h>
#include <hip/hip_cooperative_groups.h>

namespace cg = cooperative_groups;

// Problem constants (B,S,D,R) = (4,1024,1024,64)
#define SS 1024
#define DD 1024
#define RR 64
#define NB 4
#define NROWS (NB * SS)   // 4096

// ws float layout: [0, PART_F) partials (8 K-slices), [PART_F, +T_F) t, then n[NROWS]
#define PART_F ((size_t)8 * NROWS * RR)   // 2M floats = 8 MB
#define T_F    ((size_t)NROWS * RR)       // 256K floats = 1 MB
#define WS_NEED_COOP ((PART_F + T_F + NROWS) * 4)

// ===========================================================================
// Fused cooperative kernel: phase1 proj-partials -> sync -> phase2 reduce+norms
// -> sync -> phase3 distances. Grid-stride in every phase (any grid size G).
// LDS union: phase1 AT[64][34]+Pt[64][64] (6272 f), phase3 tiT/tjT[64][68]+ni+nj
// (8832 f = 35.3 KB -> 4 blocks/CU).
// ===========================================================================
__global__ __launch_bounds__(256, 4) void fused_kernel(const float* __restrict__ batch,
                                                       const float* __restrict__ proj,
                                                       float* __restrict__ ws,
                                                       float* __restrict__ out,
                                                       int G) {
    __shared__ __align__(16) float smem[8832];

    float* part = ws;
    float* t_g  = ws + PART_F;
    float* n_g  = t_g + T_F;

    const int tid = threadIdx.x;
    const int bid = blockIdx.x;
    const int tx = tid & 15;
    const int ty = tid >> 4;

    cg::grid_group grid = cg::this_grid();

    // ---------------- Phase 1: proj partials ----------------
    // 1024 units: u>>3 = 32-row tile (128 of them), u&7 = K-slice of 128.
    {
        float (*AT)[34] = (float(*)[34])smem;            // transposed A [k][row]
        float (*Pt)[64] = (float(*)[64])(smem + 2176);   // proj chunk [k][r]

        for (int u = bid; u < 1024; u += G) {
            const int row0 = (u >> 3) * 32;
            const int kb   = (u & 7) * 128;
            float acc[2][4] = {{0.f,0.f,0.f,0.f},{0.f,0.f,0.f,0.f}};

            for (int kt = 0; kt < 2; ++kt) {           // 2 tiles of BK=64
                const int k0 = kb + kt * 64;
                __syncthreads();                        // LDS reuse guard
                {
                    const int r  = tid >> 3;            // 0..31
                    const int c4 = tid & 7;             // f4 idx: c4 and c4+8
                    const float4 a0 = *reinterpret_cast<const float4*>(
                        &batch[(size_t)(row0 + r) * DD + k0 + c4 * 4]);
                    const float4 a1 = *reinterpret_cast<const float4*>(
                        &batch[(size_t)(row0 + r) * DD + k0 + (c4 + 8) * 4]);
                    AT[c4*4+0][r] = a0.x; AT[c4*4+1][r] = a0.y;
                    AT[c4*4+2][r] = a0.z; AT[c4*4+3][r] = a0.w;
                    AT[(c4+8)*4+0][r] = a1.x; AT[(c4+8)*4+1][r] = a1.y;
                    AT[(c4+8)*4+2][r] = a1.z; AT[(c4+8)*4+3][r] = a1.w;
                    const float4* psrc =
                        reinterpret_cast<const float4*>(proj + (size_t)k0 * RR);
#pragma unroll
                    for (int i = 0; i < 4; ++i)
                        reinterpret_cast<float4*>(Pt)[i * 256 + tid] = psrc[i * 256 + tid];
                }
                __syncthreads();
#pragma unroll 8
                for (int k = 0; k < 64; ++k) {
                    const float2 av = *reinterpret_cast<const float2*>(&AT[k][ty * 2]);
                    const float4 pv = *reinterpret_cast<const float4*>(&Pt[k][tx * 4]);
                    acc[0][0] = fmaf(av.x, pv.x, acc[0][0]);
                    acc[0][1] = fmaf(av.x, pv.y, acc[0][1]);
                    acc[0][2] = fmaf(av.x, pv.z, acc[0][2]);
                    acc[0][3] = fmaf(av.x, pv.w, acc[0][3]);
                    acc[1][0] = fmaf(av.y, pv.x, acc[1][0]);
                    acc[1][1] = fmaf(av.y, pv.y, acc[1][1]);
                    acc[1][2] = fmaf(av.y, pv.z, acc[1][2]);
                    acc[1][3] = fmaf(av.y, pv.w, acc[1][3]);
                }
            }
            float* slice = part + (size_t)(u & 7) * T_F;
#pragma unroll
            for (int i = 0; i < 2; ++i) {
                float4 o = {acc[i][0], acc[i][1], acc[i][2], acc[i][3]};
                *reinterpret_cast<float4*>(
                    &slice[(size_t)(row0 + ty * 2 + i) * RR + tx * 4]) = o;
            }
        }
    }

    grid.sync();

    // ---------------- Phase 2: reduce partials -> t, plus row norms ----------
    {
        const float4* p4 = reinterpret_cast<const float4*>(part);
        const int total = NROWS * RR / 4;               // 65536 f4
        for (int idx = bid * 256 + tid; idx < total; idx += G * 256) {
            float4 s = p4[idx];
#pragma unroll
            for (int kb = 1; kb < 8; ++kb) {
                const float4 v = p4[(size_t)kb * total + idx];
                s.x += v.x; s.y += v.y; s.z += v.z; s.w += v.w;
            }
            reinterpret_cast<float4*>(t_g)[idx] = s;
            float sq = s.x * s.x + s.y * s.y + s.z * s.z + s.w * s.w;
#pragma unroll
            for (int o = 1; o < 16; o <<= 1) sq += __shfl_xor(sq, o, 64);
            if ((idx & 15) == 0) n_g[idx >> 4] = sq;    // 16 f4 per row
        }
    }

    grid.sync();

    // ---------------- Phase 3: distances ------------------------------------
    {
        float (*tiT)[68] = (float(*)[68])smem;
        float (*tjT)[68] = (float(*)[68])(smem + 4352);
        float* ni = smem + 8704;
        float* nj = smem + 8768;

        for (int u = bid; u < 1024; u += G) {
            const int b   = u >> 8;
            const int rem = u & 255;
            const int i0  = (rem >> 4) * 64;
            const int j0  = (rem & 15) * 64;

            __syncthreads();                            // LDS reuse guard
            for (int idx = tid; idx < 2048; idx += 256) {
                const int tile = idx >> 10;
                const int e    = idx & 1023;
                const int row  = e >> 4;
                const int rseg = e & 15;
                const int srow = b * SS + (tile ? j0 : i0) + row;
                const float4 v = reinterpret_cast<const float4*>(t_g)[srow * 16 + rseg];
                float (*dst)[68] = tile ? tjT : tiT;
                dst[rseg*4+0][row] = v.x;
                dst[rseg*4+1][row] = v.y;
                dst[rseg*4+2][row] = v.z;
                dst[rseg*4+3][row] = v.w;
            }
            if (tid < 64)       ni[tid]      = n_g[b * SS + i0 + tid];
            else if (tid < 128) nj[tid - 64] = n_g[b * SS + j0 + (tid - 64)];
            __syncthreads();

            float acc[4][4];
#pragma unroll
            for (int i = 0; i < 4; ++i)
#pragma unroll
                for (int j = 0; j < 4; ++j) acc[i][j] = 0.0f;

#pragma unroll 4
            for (int r = 0; r < RR; ++r) {
                const float4 av = *reinterpret_cast<const float4*>(&tiT[r][ty * 4]);
                const float4 bv = *reinterpret_cast<const float4*>(&tjT[r][tx * 4]);
                const float a[4] = {av.x, av.y, av.z, av.w};
                const float c[4] = {bv.x, bv.y, bv.z, bv.w};
#pragma unroll
                for (int i = 0; i < 4; ++i)
#pragma unroll
                    for (int j = 0; j < 4; ++j)
                        acc[i][j] = fmaf(a[i], c[j], acc[i][j]);
            }

            const float nrow[4] = {ni[ty*4+0], ni[ty*4+1], ni[ty*4+2], ni[ty*4+3]};
            const float ncol[4] = {nj[tx*4+0], nj[tx*4+1], nj[tx*4+2], nj[tx*4+3]};
#pragma unroll
            for (int i = 0; i < 4; ++i) {
                float4 o;
                o.x = fmaf(-2.0f, acc[i][0], nrow[i] + ncol[0]);
                o.y = fmaf(-2.0f, acc[i][1], nrow[i] + ncol[1]);
                o.z = fmaf(-2.0f, acc[i][2], nrow[i] + ncol[2]);
                o.w = fmaf(-2.0f, acc[i][3], nrow[i] + ncol[3]);
                *reinterpret_cast<float4*>(
                    &out[((size_t)(b * SS + i0 + ty * 4 + i)) * SS + j0 + tx * 4]) = o;
            }
        }
    }
}

// ===========================================================================
// Fallback path (proven round-6 pipeline): proj partials + reduce + dist.
// ===========================================================================
#define PROJ_ROWS 64
#define PROJ_BK 64
#define PROJ_KSPLIT 8
#define PROJ_KSLICE (DD / PROJ_KSPLIT)
#define ATSTRIDE 68
#define TPAD 68

template <bool ATOMIC>
__global__ __launch_bounds__(256) void proj_kernel(const float* __restrict__ batch,
                                                   const float* __restrict__ proj,
                                                   float* __restrict__ dst) {
    __shared__ __align__(16) float AT[PROJ_BK][ATSTRIDE];
    __shared__ __align__(16) float Pt[PROJ_BK][RR];
    const int tid  = threadIdx.x;
    const int row0 = blockIdx.x * PROJ_ROWS;
    const int kbase = blockIdx.y * PROJ_KSLICE;
    const int tx = tid & 15, ty = tid >> 4, srow = ty, sk4 = tx;
    float acc[4][4] = {{0.0f}};
    float4 a_reg[4], p_reg[4];
    auto load_tile = [&](int kt) {
        const int kt0 = kbase + kt * PROJ_BK;
#pragma unroll
        for (int i = 0; i < 4; ++i) {
            a_reg[i] = *reinterpret_cast<const float4*>(
                &batch[(size_t)(row0 + i * 16 + srow) * DD + kt0 + sk4 * 4]);
            p_reg[i] = reinterpret_cast<const float4*>(
                &proj[(size_t)kt0 * RR])[i * 256 + tid];
        }
    };
    auto write_tile = [&]() {
#pragma unroll
        for (int i = 0; i < 4; ++i) {
            AT[sk4*4+0][i*16+srow] = a_reg[i].x;
            AT[sk4*4+1][i*16+srow] = a_reg[i].y;
            AT[sk4*4+2][i*16+srow] = a_reg[i].z;
            AT[sk4*4+3][i*16+srow] = a_reg[i].w;
            reinterpret_cast<float4*>(Pt)[i * 256 + tid] = p_reg[i];
        }
    };
    auto compute = [&]() {
#pragma unroll 8
        for (int k = 0; k < PROJ_BK; ++k) {
            const float4 av = *reinterpret_cast<const float4*>(&AT[k][ty * 4]);
            const float4 pv = *reinterpret_cast<const float4*>(&Pt[k][tx * 4]);
            const float a[4] = {av.x, av.y, av.z, av.w};
            const float p[4] = {pv.x, pv.y, pv.z, pv.w};
#pragma unroll
            for (int i = 0; i < 4; ++i)
#pragma unroll
                for (int j = 0; j < 4; ++j)
                    acc[i][j] = fmaf(a[i], p[j], acc[i][j]);
        }
    };
    load_tile(0); write_tile(); __syncthreads();
    load_tile(1); compute(); __syncthreads();
    write_tile(); __syncthreads(); compute();
    if (ATOMIC) {
#pragma unroll
        for (int i = 0; i < 4; ++i)
#pragma unroll
            for (int j = 0; j < 4; ++j)
                atomicAdd(&dst[(size_t)(row0+ty*4+i)*RR + tx*4+j], acc[i][j]);
    } else {
        float* slice = dst + (size_t)blockIdx.y * NROWS * RR;
#pragma unroll
        for (int i = 0; i < 4; ++i) {
            float4 o = {acc[i][0], acc[i][1], acc[i][2], acc[i][3]};
            *reinterpret_cast<float4*>(&slice[(size_t)(row0+ty*4+i)*RR + tx*4]) = o;
        }
    }
}

__global__ __launch_bounds__(256) void reduce_kernel(const float* __restrict__ part,
                                                     float* __restrict__ t) {
    const int idx = blockIdx.x * 256 + threadIdx.x;
    const float4* p4 = reinterpret_cast<const float4*>(part);
    float4 s = p4[idx];
#pragma unroll
    for (int kb = 1; kb < PROJ_KSPLIT; ++kb) {
        const float4 v = p4[(size_t)kb * (NROWS * RR / 4) + idx];
        s.x += v.x; s.y += v.y; s.z += v.z; s.w += v.w;
    }
    reinterpret_cast<float4*>(t)[idx] = s;
}

__global__ __launch_bounds__(256) void zero_kernel(float* __restrict__ t) {
    const int idx = blockIdx.x * 256 + threadIdx.x;
    reinterpret_cast<float4*>(t)[idx] = {0.0f, 0.0f, 0.0f, 0.0f};
}

__global__ __launch_bounds__(256) void dist_kernel(const float* __restrict__ t,
                                                   float* __restrict__ out) {
    __shared__ __align__(16) float tiT[RR][TPAD];
    __shared__ __align__(16) float tjT[RR][TPAD];
    __shared__ float ni[64];
    __shared__ float nj[64];
    const int b = blockIdx.z, i0 = blockIdx.y * 64, j0 = blockIdx.x * 64;
    const int tid = threadIdx.x;
    for (int idx = tid; idx < 2048; idx += 256) {
        const int tile = idx >> 10, e = idx & 1023, row = e >> 4, rseg = e & 15;
        const int src_row = b * SS + (tile ? j0 : i0) + row;
        const float4 v = *reinterpret_cast<const float4*>(&t[(size_t)src_row * RR + rseg * 4]);
        float (*dst)[TPAD] = tile ? tjT : tiT;
        dst[rseg*4+0][row] = v.x; dst[rseg*4+1][row] = v.y;
        dst[rseg*4+2][row] = v.z; dst[rseg*4+3][row] = v.w;
    }
    __syncthreads();
    if (tid < 128) {
        const int row = tid & 63;
        float (*src)[TPAD] = (tid >> 6) ? tjT : tiT;
        float s = 0.0f;
#pragma unroll
        for (int r = 0; r < RR; ++r) { const float v = src[r][row]; s = fmaf(v, v, s); }
        if (tid >> 6) nj[row] = s; else ni[row] = s;
    }
    __syncthreads();
    const int tx = tid & 15, ty = tid >> 4;
    float acc[4][4];
#pragma unroll
    for (int i = 0; i < 4; ++i)
#pragma unroll
        for (int j = 0; j < 4; ++j) acc[i][j] = 0.0f;
#pragma unroll 4
    for (int r = 0; r < RR; ++r) {
        const float4 av = *reinterpret_cast<const float4*>(&tiT[r][ty * 4]);
        const float4 bv = *reinterpret_cast<const float4*>(&tjT[r][tx * 4]);
        const float a[4] = {av.x, av.y, av.z, av.w};
        const float c[4] = {bv.x, bv.y, bv.z, bv.w};
#pragma unroll
        for (int i = 0; i < 4; ++i)
#pragma unroll
            for (int j = 0; j < 4; ++j)
                acc[i][j] = fmaf(a[i], c[j], acc[i][j]);
    }
    const float nrow[4] = {ni[ty*4+0], ni[ty*4+1], ni[ty*4+2], ni[ty*4+3]};
    const float ncol[4] = {nj[tx*4+0], nj[tx*4+1], nj[tx*4+2], nj[tx*4+3]};
#pragma unroll
    for (int i = 0; i < 4; ++i) {
        float4 o;
        o.x = fmaf(-2.0f, acc[i][0], nrow[i] + ncol[0]);
        o.y = fmaf(-2.0f, acc[i][1], nrow[i] + ncol[1]);
        o.z = fmaf(-2.0f, acc[i][2], nrow[i] + ncol[2]);
        o.w = fmaf(-2.0f, acc[i][3], nrow[i] + ncol[3]);
        *reinterpret_cast<float4*>(
            &out[((size_t)(b * SS + i0 + ty * 4 + i)) * SS + j0 + tx * 4]) = o;
    }
}

// ===========================================================================
extern "C" void kernel_launch(void* const* d_in, const int* in_sizes, int n_in,
                              void* d_out, int out_size, void* d_ws, size_t ws_size,
                              hipStream_t stream) {
    const float* batch = (const float*)d_in[0];
    const float* proj  = (const float*)d_in[1];
    float* out = (float*)d_out;
    float* ws  = (float*)d_ws;

    // -------- Main path: single cooperative kernel --------
    if (ws_size >= WS_NEED_COOP) {
        int dev = 0;
        hipGetDevice(&dev);
        int cus = 0;
        hipDeviceGetAttribute(&cus, hipDeviceAttributeMultiprocessorCount, dev);
        int perCU = 0;
        hipError_t oe = hipOccupancyMaxActiveBlocksPerMultiprocessor(
            &perCU, fused_kernel, 256, 0);
        if (oe == hipSuccess && perCU > 0 && cus > 0) {
            int G = perCU * cus;
            if (G > 1024) G = 1024;
            void* args[] = {(void*)&batch, (void*)&proj, (void*)&ws, (void*)&out,
                            (void*)&G};
            if (hipLaunchCooperativeKernel(fused_kernel, dim3(G), dim3(256),
                                           args, 0, stream) == hipSuccess)
                return;
        }
    }

    // -------- Fallback 1: proven 3-kernel partials path (round 6, 41.4us) ----
    dim3 gA(NROWS / PROJ_ROWS, PROJ_KSPLIT, 1);
    dim3 gB(SS / 64, SS / 64, NB);
    if (ws_size >= (PART_F + T_F) * 4) {
        float* part = ws;
        float* t    = ws + PART_F;
        proj_kernel<false><<<gA, 256, 0, stream>>>(batch, proj, part);
        reduce_kernel<<<NROWS * RR / (256 * 4), 256, 0, stream>>>(part, t);
        dist_kernel<<<gB, 256, 0, stream>>>(t, out);
    } else {
        // -------- Fallback 2: tiny ws — zero + atomic combine ----------------
        float* t = ws;
        zero_kernel<<<NROWS * RR / (256 * 4), 256, 0, stream>>>(t);
        proj_kernel<true><<<gA, 256, 0, stream>>>(batch, proj, t);
        dist_kernel<<<gB, 256, 0, stream>>>(t, out);
    }
}

// Round 10
// 41.755 us; speedup vs baseline: 5.2899x; 5.2899x over previous
//
#include <hip/hip_runtime.h>

// Problem constants (B,S,D,R) = (4,1024,1024,64)
#define SS 1024
#define DD 1024
#define RR 64
#define NB 4
#define NROWS (NB * SS)   // 4096

// ---- proj v3: 256-row x 64-col tile, KSPLIT=16, 8x8 per thread ------------
#define P_ROWS 256
#define P_KSPLIT 16
#define P_BK 64                       // = DD / P_KSPLIT, one tile, no kt loop
#define ATS 260                       // AT row stride (floats): 1040B, 16B-aligned

#define T_F    ((size_t)NROWS * RR)            // 256K floats = 1 MB
#define PART_F ((size_t)P_KSPLIT * T_F)        // 4M floats = 16 MB
#define WS_NEED ((PART_F + T_F) * 4)           // 17 MB

// ---------------------------------------------------------------------------
// proj16: part[slice][row][r] = sum_{k in slice} batch[row][k] * proj[k][r]
// grid 256 = 16 row-strips x 16 K-slices, block 256 threads.
// LDS: AT[64][260] transposed batch (65KB) + Pt[64][64] proj chunk (16KB).
// Thread tile 8x8 -> 1 B LDS per FMA -> FMA-bound (~3.4us model).
// ---------------------------------------------------------------------------
__global__ __launch_bounds__(256) void proj16_kernel(const float* __restrict__ batch,
                                                     const float* __restrict__ proj,
                                                     float* __restrict__ part) {
    __shared__ __align__(16) float AT[P_BK][ATS];   // [k][row]
    __shared__ __align__(16) float Pt[P_BK][RR];    // [k][r]

    const int tid   = threadIdx.x;
    const int strip = blockIdx.x >> 4;        // 0..15
    const int slice = blockIdx.x & 15;        // 0..15
    const int row0  = strip * P_ROWS;
    const int kbase = slice * P_BK;

    // ---- stage batch transposed: 256 rows x 64 k ----
    {
        const int rbase = tid >> 4;           // 0..15
        const int k4    = tid & 15;           // float4 index along k
        float4 v[16];
#pragma unroll
        for (int p = 0; p < 16; ++p) {
            const int row = rbase + p * 16;
            v[p] = *reinterpret_cast<const float4*>(
                &batch[(size_t)(row0 + row) * DD + kbase + k4 * 4]);
        }
#pragma unroll
        for (int p = 0; p < 16; ++p) {
            const int row = rbase + p * 16;
            AT[k4 * 4 + 0][row] = v[p].x;
            AT[k4 * 4 + 1][row] = v[p].y;
            AT[k4 * 4 + 2][row] = v[p].z;
            AT[k4 * 4 + 3][row] = v[p].w;
        }
        // proj chunk: contiguous 16KB -> linear copy
        const float4* psrc = reinterpret_cast<const float4*>(proj + (size_t)kbase * RR);
#pragma unroll
        for (int i = 0; i < 4; ++i)
            reinterpret_cast<float4*>(Pt)[i * 256 + tid] = psrc[i * 256 + tid];
    }
    __syncthreads();

    // ---- compute: 8 rows x 8 cols per thread ----
    const int tx = tid & 7;    // col group: cols tx*8..+7
    const int ty = tid >> 3;   // row group: rows ty*8..+7 (0..31)

    float acc[8][8];
#pragma unroll
    for (int i = 0; i < 8; ++i)
#pragma unroll
        for (int j = 0; j < 8; ++j) acc[i][j] = 0.0f;

#pragma unroll 4
    for (int k = 0; k < P_BK; ++k) {
        const float4 a0 = *reinterpret_cast<const float4*>(&AT[k][ty * 8 + 0]);
        const float4 a1 = *reinterpret_cast<const float4*>(&AT[k][ty * 8 + 4]);
        const float4 p0 = *reinterpret_cast<const float4*>(&Pt[k][tx * 8 + 0]);
        const float4 p1 = *reinterpret_cast<const float4*>(&Pt[k][tx * 8 + 4]);
        const float a[8] = {a0.x, a0.y, a0.z, a0.w, a1.x, a1.y, a1.z, a1.w};
        const float p[8] = {p0.x, p0.y, p0.z, p0.w, p1.x, p1.y, p1.z, p1.w};
#pragma unroll
        for (int i = 0; i < 8; ++i)
#pragma unroll
            for (int j = 0; j < 8; ++j)
                acc[i][j] = fmaf(a[i], p[j], acc[i][j]);
    }

    // ---- store partial slice ----
    float* slice_p = part + (size_t)slice * T_F;
#pragma unroll
    for (int i = 0; i < 8; ++i) {
        const size_t base = (size_t)(row0 + ty * 8 + i) * RR + tx * 8;
        float4 o0 = {acc[i][0], acc[i][1], acc[i][2], acc[i][3]};
        float4 o1 = {acc[i][4], acc[i][5], acc[i][6], acc[i][7]};
        *reinterpret_cast<float4*>(&slice_p[base + 0]) = o0;
        *reinterpret_cast<float4*>(&slice_p[base + 4]) = o1;
    }
}

// Sum the 16 K-slice partials -> t. 65536 float4, one per thread, 256 blocks.
__global__ __launch_bounds__(256) void reduce16_kernel(const float* __restrict__ part,
                                                       float* __restrict__ t) {
    const int idx = blockIdx.x * 256 + threadIdx.x;   // 0..65535
    const float4* p4 = reinterpret_cast<const float4*>(part);
    float4 s = p4[idx];
#pragma unroll
    for (int sl = 1; sl < P_KSPLIT; ++sl) {
        const float4 v = p4[(size_t)sl * (T_F / 4) + idx];
        s.x += v.x; s.y += v.y; s.z += v.z; s.w += v.w;
    }
    reinterpret_cast<float4*>(t)[idx] = s;
}

// ---------------------------------------------------------------------------
// dist (unchanged, measured ~9us): out[b][i][j] = n_i + n_j - 2 * t_i . t_j
// ---------------------------------------------------------------------------
#define TPAD 68

__global__ __launch_bounds__(256) void dist_kernel(const float* __restrict__ t,
                                                   float* __restrict__ out) {
    __shared__ __align__(16) float tiT[RR][TPAD];
    __shared__ __align__(16) float tjT[RR][TPAD];
    __shared__ float ni[64];
    __shared__ float nj[64];

    const int b  = blockIdx.z;
    const int i0 = blockIdx.y * 64;
    const int j0 = blockIdx.x * 64;
    const int tid = threadIdx.x;

    for (int idx = tid; idx < 2048; idx += 256) {
        const int tile = idx >> 10;
        const int e    = idx & 1023;
        const int row  = e >> 4;
        const int rseg = e & 15;
        const int src_row = b * SS + (tile ? j0 : i0) + row;
        const float4 v =
            *reinterpret_cast<const float4*>(&t[(size_t)src_row * RR + rseg * 4]);
        float (*dst)[TPAD] = tile ? tjT : tiT;
        dst[rseg * 4 + 0][row] = v.x;
        dst[rseg * 4 + 1][row] = v.y;
        dst[rseg * 4 + 2][row] = v.z;
        dst[rseg * 4 + 3][row] = v.w;
    }
    __syncthreads();

    if (tid < 128) {
        const int row = tid & 63;
        float (*src)[TPAD] = (tid >> 6) ? tjT : tiT;
        float s = 0.0f;
#pragma unroll
        for (int r = 0; r < RR; ++r) {
            const float v = src[r][row];
            s = fmaf(v, v, s);
        }
        if (tid >> 6) nj[row] = s; else ni[row] = s;
    }
    __syncthreads();

    const int tx = tid & 15;
    const int ty = tid >> 4;

    float acc[4][4];
#pragma unroll
    for (int i = 0; i < 4; ++i)
#pragma unroll
        for (int j = 0; j < 4; ++j) acc[i][j] = 0.0f;

#pragma unroll 4
    for (int r = 0; r < RR; ++r) {
        const float4 av = *reinterpret_cast<const float4*>(&tiT[r][ty * 4]);
        const float4 bv = *reinterpret_cast<const float4*>(&tjT[r][tx * 4]);
        const float a[4] = {av.x, av.y, av.z, av.w};
        const float c[4] = {bv.x, bv.y, bv.z, bv.w};
#pragma unroll
        for (int i = 0; i < 4; ++i)
#pragma unroll
            for (int j = 0; j < 4; ++j)
                acc[i][j] = fmaf(a[i], c[j], acc[i][j]);
    }

    const float nrow[4] = {ni[ty*4+0], ni[ty*4+1], ni[ty*4+2], ni[ty*4+3]};
    const float ncol[4] = {nj[tx*4+0], nj[tx*4+1], nj[tx*4+2], nj[tx*4+3]};
#pragma unroll
    for (int i = 0; i < 4; ++i) {
        float4 o;
        o.x = fmaf(-2.0f, acc[i][0], nrow[i] + ncol[0]);
        o.y = fmaf(-2.0f, acc[i][1], nrow[i] + ncol[1]);
        o.z = fmaf(-2.0f, acc[i][2], nrow[i] + ncol[2]);
        o.w = fmaf(-2.0f, acc[i][3], nrow[i] + ncol[3]);
        *reinterpret_cast<float4*>(
            &out[((size_t)(b * SS + i0 + ty * 4 + i)) * SS + j0 + tx * 4]) = o;
    }
}

// ---- fallback bits (tiny ws): own zero + atomic-combine proj --------------
__global__ __launch_bounds__(256) void zero_kernel(float* __restrict__ t) {
    const int idx = blockIdx.x * 256 + threadIdx.x;
    reinterpret_cast<float4*>(t)[idx] = {0.0f, 0.0f, 0.0f, 0.0f};
}

__global__ __launch_bounds__(256) void proj_atomic_kernel(const float* __restrict__ batch,
                                                          const float* __restrict__ proj,
                                                          float* __restrict__ t) {
    __shared__ __align__(16) float AT[64][68];
    __shared__ __align__(16) float Pt[64][RR];
    const int tid = threadIdx.x;
    const int row0 = blockIdx.x * 64;
    const int kbase = blockIdx.y * 128;
    const int tx = tid & 15, ty = tid >> 4;
    float acc[4][4] = {{0.0f}};
    for (int kt = 0; kt < 2; ++kt) {
        const int k0 = kbase + kt * 64;
        __syncthreads();
#pragma unroll
        for (int i = 0; i < 4; ++i) {
            const float4 a = *reinterpret_cast<const float4*>(
                &batch[(size_t)(row0 + i * 16 + ty) * DD + k0 + tx * 4]);
            AT[tx*4+0][i*16+ty] = a.x; AT[tx*4+1][i*16+ty] = a.y;
            AT[tx*4+2][i*16+ty] = a.z; AT[tx*4+3][i*16+ty] = a.w;
            reinterpret_cast<float4*>(Pt)[i * 256 + tid] =
                reinterpret_cast<const float4*>(proj + (size_t)k0 * RR)[i * 256 + tid];
        }
        __syncthreads();
#pragma unroll 8
        for (int k = 0; k < 64; ++k) {
            const float4 av = *reinterpret_cast<const float4*>(&AT[k][ty * 4]);
            const float4 pv = *reinterpret_cast<const float4*>(&Pt[k][tx * 4]);
            const float a[4] = {av.x, av.y, av.z, av.w};
            const float p[4] = {pv.x, pv.y, pv.z, pv.w};
#pragma unroll
            for (int i = 0; i < 4; ++i)
#pragma unroll
                for (int j = 0; j < 4; ++j)
                    acc[i][j] = fmaf(a[i], p[j], acc[i][j]);
        }
    }
#pragma unroll
    for (int i = 0; i < 4; ++i)
#pragma unroll
        for (int j = 0; j < 4; ++j)
            atomicAdd(&t[(size_t)(row0 + ty*4 + i) * RR + tx*4 + j], acc[i][j]);
}

// ---------------------------------------------------------------------------
extern "C" void kernel_launch(void* const* d_in, const int* in_sizes, int n_in,
                              void* d_out, int out_size, void* d_ws, size_t ws_size,
                              hipStream_t stream) {
    const float* batch = (const float*)d_in[0];  // (4,1024,1024) f32
    const float* proj  = (const float*)d_in[1];  // (1024,64) f32
    float* out = (float*)d_out;                  // (4,1024,1024) f32
    float* ws  = (float*)d_ws;

    dim3 gB(SS / 64, SS / 64, NB);

    if (ws_size >= WS_NEED) {
        float* part = ws;                        // 16 MB
        float* t    = ws + PART_F;               // 1 MB
        proj16_kernel<<<256, 256, 0, stream>>>(batch, proj, part);
        reduce16_kernel<<<256, 256, 0, stream>>>(part, t);
        dist_kernel<<<gB, 256, 0, stream>>>(t, out);
    } else {
        float* t = ws;
        zero_kernel<<<T_F / (256 * 4), 256, 0, stream>>>(t);
        dim3 gA(NROWS / 64, 8, 1);
        proj_atomic_kernel<<<gA, 256, 0, stream>>>(batch, proj, t);
        dist_kernel<<<gB, 256, 0, stream>>>(t, out);
    }
}